// Round 1
// baseline (678.801 us; speedup 1.0000x reference)
//
#include <hip/hip_runtime.h>

#define NT 1024          // threads per conv block
#define B_SZ 4
#define D_MODEL 1024
#define SEQ_LEN 8192     // L
// FFT: real length 16384 packed as 8192 complex
#define N2 8192

static __device__ __forceinline__ int padi(int p) { return p + (p >> 4); }
static __device__ __forceinline__ float2 cmul(float2 a, float2 b) {
    return make_float2(a.x * b.x - a.y * b.y, a.x * b.y + a.y * b.x);
}

// ---------------- MLP: h3[j][16] = sin-MLP(z[j]) ----------------
__global__ void hyena_mlp(const float* __restrict__ z,
                          const float* __restrict__ W1, const float* __restrict__ b1,
                          const float* __restrict__ W2, const float* __restrict__ b2,
                          const float* __restrict__ W3, const float* __restrict__ b3,
                          const float* __restrict__ freq,
                          float* __restrict__ h3) {
    int j = blockIdx.x * blockDim.x + threadIdx.x;
    if (j >= SEQ_LEN) return;
    float z0 = z[3 * j + 0], z1 = z[3 * j + 1], z2 = z[3 * j + 2];
    float ha[16], hb[16];
#pragma unroll
    for (int o = 0; o < 16; ++o) {
        float acc = b1[o] + z0 * W1[o] + z1 * W1[16 + o] + z2 * W1[32 + o];
        ha[o] = sinf(freq[o] * acc);
    }
#pragma unroll
    for (int p = 0; p < 16; ++p) {
        float acc = b2[p];
#pragma unroll
        for (int o = 0; o < 16; ++o) acc += ha[o] * W2[o * 16 + p];
        hb[p] = sinf(freq[p] * acc);
    }
#pragma unroll
    for (int q = 0; q < 16; ++q) {
        float acc = b3[q];
#pragma unroll
        for (int o = 0; o < 16; ++o) acc += hb[o] * W3[o * 16 + q];
        h3[j * 16 + q] = sinf(freq[q] * acc);
    }
}

// ---------------- 8192-pt complex FFT in LDS (radix-2) ----------------
// forward: DIF, natural in -> bit-reversed out, twiddle e^{-2pi i t/8192}
__device__ __forceinline__ void fft8k_fwd(float2* c, const float2* tw, const float2* tw32, int tid) {
    for (int m = 12; m >= 0; --m) {
        int h = 1 << m;
        for (int bf = tid; bf < 4096; bf += NT) {
            int j = bf & (h - 1);
            int i = ((bf >> m) << (m + 1)) | j;
            float2 w = (m >= 6) ? tw[padi(j << (12 - m))] : tw32[padi(j << (5 - m))];
            float2 u = c[padi(i)];
            float2 v = c[padi(i + h)];
            c[padi(i)] = make_float2(u.x + v.x, u.y + v.y);
            float2 t = make_float2(u.x - v.x, u.y - v.y);
            c[padi(i + h)] = cmul(t, w);
        }
        __syncthreads();
    }
}

// inverse: DIT, bit-reversed in -> natural out, twiddle conj, NO 1/N scaling
__device__ __forceinline__ void fft8k_inv(float2* c, const float2* tw, const float2* tw32, int tid) {
    for (int m = 0; m <= 12; ++m) {
        int h = 1 << m;
        for (int bf = tid; bf < 4096; bf += NT) {
            int j = bf & (h - 1);
            int i = ((bf >> m) << (m + 1)) | j;
            float2 w = (m >= 6) ? tw[padi(j << (12 - m))] : tw32[padi(j << (5 - m))];
            w.y = -w.y;
            float2 t = cmul(c[padi(i + h)], w);
            float2 u = c[padi(i)];
            c[padi(i)] = make_float2(u.x + t.x, u.y + t.y);
            c[padi(i + h)] = make_float2(u.x - t.x, u.y - t.y);
        }
        __syncthreads();
    }
}

// ---------------- main: one block per channel d ----------------
// LDS: data 8704 f2 | tw 4352 f2 | tw32 40 f2  => 13096*8 = 104768 B
#define SMEM_F2 (8704 + 4352 + 40)

__global__ __launch_bounds__(NT, 1)
void hyena_conv(const float* __restrict__ h3, const float* __restrict__ Wout,
                const float* __restrict__ x, const float* __restrict__ bias,
                float* __restrict__ out) {
    extern __shared__ float2 smem[];
    float2* c    = smem;
    float2* tw   = smem + 8704;
    float2* tw32 = tw + 4352;
    const int tid = threadIdx.x;
    const int d   = blockIdx.x;
    const float PI = 3.14159265358979323846f;

    // twiddle tables: tw[t] = e^{-i pi t/4096}, t in [0,4096)
    for (int t = tid; t < 4096; t += NT) {
        float s_, c_;
        sincosf((PI / 4096.0f) * (float)t, &s_, &c_);
        tw[padi(t)] = make_float2(c_, -s_);
    }
    if (tid < 32) {
        float s_, c_;
        sincosf((PI / 32.0f) * (float)tid, &s_, &c_);  // t = tid<<7
        tw32[padi(tid)] = make_float2(c_, -s_);
    }

    // ---- build filter row k_d, packed: c[n] = (k[2n], k[2n+1]) ----
    const float dmin = -3.0701134573253941f;   // log(0.01)/1.5
    const float dmax = -15.350567286626971f;   // log(0.01)/0.3
    float absd = fabsf(dmin + (dmax - dmin) * ((float)d / 1023.0f));
    float wcol[16];
#pragma unroll
    for (int o = 0; o < 16; ++o) wcol[o] = Wout[o * D_MODEL + d];

    for (int n = tid; n < 4096; n += NT) {
        int j0 = 2 * n;
        const float* r0 = h3 + (size_t)j0 * 16;
        float acc0 = 0.f, acc1 = 0.f;
#pragma unroll
        for (int o = 0; o < 16; ++o) {
            acc0 += r0[o] * wcol[o];
            acc1 += r0[16 + o] * wcol[o];
        }
        float t0 = (float)j0 * (1.0f / 8191.0f);
        float t1 = (float)(j0 + 1) * (1.0f / 8191.0f);
        c[padi(n)] = make_float2(acc0 * __expf(-t0 * absd), acc1 * __expf(-t1 * absd));
    }
    for (int n = 4096 + tid; n < 8192; n += NT) c[padi(n)] = make_float2(0.f, 0.f);
    __syncthreads();

    fft8k_fwd(c, tw, tw32, tid);

    // ---- unpack rfft(K) into registers, pair-packed, scaled by 1/(2*N2) ----
    const float s = 1.0f / 16384.0f;
    float4 Kreg[4];
#pragma unroll
    for (int q = 0; q < 4; ++q) {
        int k = q * NT + tid;
        if (k == 0) {
            float2 C0 = c[padi(0)];
            float2 C4 = c[padi(1)];        // rev13(4096) = 1
            Kreg[q] = make_float4((C0.x + C0.y) * s, (C0.x - C0.y) * s, C4.x * s, -C4.y * s);
        } else {
            int p1 = __brev((unsigned)k) >> 19;
            int p2 = __brev((unsigned)(8192 - k)) >> 19;
            float2 Ck = c[padi(p1)], Cm = c[padi(p2)];
            float2 A  = make_float2(0.5f * (Ck.x + Cm.x), 0.5f * (Ck.y - Cm.y));
            float2 Bc = make_float2(0.5f * (Ck.x - Cm.x), 0.5f * (Ck.y + Cm.y));
            float2 B  = make_float2(Bc.y, -Bc.x);      // -i * Bc
            float sw, cw;
            sincosf((PI / 8192.0f) * (float)k, &sw, &cw);
            float2 w  = make_float2(cw, -sw);          // e^{-2pi i k/16384}
            float2 wB = cmul(w, B);
            Kreg[q] = make_float4((A.x + wB.x) * s, (A.y + wB.y) * s,
                                  (A.x - wB.x) * s, -(A.y - wB.y) * s);  // K[k], conj-pair K[N2-k]
        }
    }
    __syncthreads();

    const float bd = bias[d];
    for (int b = 0; b < B_SZ; ++b) {
        const float2* xr = (const float2*)(x + ((size_t)b * D_MODEL + d) * SEQ_LEN);
        float2* orow = (float2*)(out + ((size_t)b * D_MODEL + d) * SEQ_LEN);

        for (int n = tid; n < 4096; n += NT) c[padi(n)] = xr[n];
        for (int n = 4096 + tid; n < 8192; n += NT) c[padi(n)] = make_float2(0.f, 0.f);
        __syncthreads();

        fft8k_fwd(c, tw, tw32, tid);

        // pointwise: unpack X, Y = X*K, repack (halves dropped; 1/N2 folded into Kreg)
#pragma unroll
        for (int q = 0; q < 4; ++q) {
            int k = q * NT + tid;
            float4 Kp = Kreg[q];
            if (k == 0) {
                float2 C0 = c[padi(0)];
                float Y0 = (C0.x + C0.y) * Kp.x;
                float YN = (C0.x - C0.y) * Kp.y;
                c[padi(0)] = make_float2(Y0 + YN, Y0 - YN);
                float2 C4 = c[padi(1)];
                float2 Y4 = cmul(make_float2(C4.x, -C4.y), make_float2(Kp.z, Kp.w));
                c[padi(1)] = make_float2(2.f * Y4.x, -2.f * Y4.y);
            } else {
                int p1 = __brev((unsigned)k) >> 19;
                int p2 = __brev((unsigned)(8192 - k)) >> 19;
                float2 Ck = c[padi(p1)], Cm = c[padi(p2)];
                float2 A  = make_float2(0.5f * (Ck.x + Cm.x), 0.5f * (Ck.y - Cm.y));
                float2 Bc = make_float2(0.5f * (Ck.x - Cm.x), 0.5f * (Ck.y + Cm.y));
                float2 B  = make_float2(Bc.y, -Bc.x);
                float sw, cw;
                sincosf((PI / 8192.0f) * (float)k, &sw, &cw);
                float2 w  = make_float2(cw, -sw);
                float2 wB = cmul(w, B);
                float2 Xk = make_float2(A.x + wB.x, A.y + wB.y);
                float2 Xm = make_float2(A.x - wB.x, -(A.y - wB.y));   // conj(A - wB)
                float2 Yk = cmul(Xk, make_float2(Kp.x, Kp.y));
                float2 Ym = cmul(Xm, make_float2(Kp.z, Kp.w));
                float2 A2 = make_float2(Yk.x + Ym.x, Yk.y - Ym.y);    // Yk + conj(Ym)
                float2 Bt = make_float2(Yk.x - Ym.x, Yk.y + Ym.y);    // Yk - conj(Ym)
                float2 B2 = cmul(Bt, make_float2(w.x, -w.y));         // * conj(w)
                c[padi(p1)] = make_float2(A2.x - B2.y, A2.y + B2.x);  // A2 + i B2
                c[padi(p2)] = make_float2(A2.x + B2.y, B2.x - A2.y);  // conj(A2) + i conj(B2)
            }
        }
        __syncthreads();

        fft8k_inv(c, tw, tw32, tid);

        // y[2n],y[2n+1] = Re,Im of c[n]  (only first half of the 16384 conv needed)
        for (int n = tid; n < 4096; n += NT) {
            float2 cy = c[padi(n)];
            float2 xv = xr[n];
            orow[n] = make_float2(cy.x + xv.x * bd, cy.y + xv.y * bd);
        }
        __syncthreads();   // before next batch overwrites c
    }
}

extern "C" void kernel_launch(void* const* d_in, const int* in_sizes, int n_in,
                              void* d_out, int out_size, void* d_ws, size_t ws_size,
                              hipStream_t stream) {
    const float* x    = (const float*)d_in[0];
    // d_in[1] = L (int, 8192) — compile-time constant here
    const float* z    = (const float*)d_in[2];
    const float* W1   = (const float*)d_in[3];
    const float* b1   = (const float*)d_in[4];
    const float* W2   = (const float*)d_in[5];
    const float* b2   = (const float*)d_in[6];
    const float* W3   = (const float*)d_in[7];
    const float* b3   = (const float*)d_in[8];
    const float* Wout = (const float*)d_in[9];
    const float* freq = (const float*)d_in[10];
    const float* bias = (const float*)d_in[11];
    float* out = (float*)d_out;
    float* h3  = (float*)d_ws;   // 8192*16 floats = 512 KB

    hipLaunchKernelGGL(hyena_mlp, dim3(SEQ_LEN / 256), dim3(256), 0, stream,
                       z, W1, b1, W2, b2, W3, b3, freq, h3);

    size_t smem_bytes = (size_t)SMEM_F2 * sizeof(float2);   // 104768
    static bool attr_set = false;
    if (!attr_set) {
        (void)hipFuncSetAttribute((const void*)hyena_conv,
                                  hipFuncAttributeMaxDynamicSharedMemorySize,
                                  (int)smem_bytes);
        attr_set = true;
    }
    hipLaunchKernelGGL(hyena_conv, dim3(D_MODEL), dim3(NT), smem_bytes, stream,
                       h3, Wout, x, bias, out);
}